// Round 2
// baseline (219.699 us; speedup 1.0000x reference)
//
#include <hip/hip_runtime.h>
#include <hip/hip_bf16.h>
#include <math.h>

#define MARGIN_C 0.3f
#define CLST_SCALE 0.8f
#define SEP_SCALE 0.08f
#define DIV_SCALE 0.01f
#define CONTRASTIVE_SCALE 0.1f

#define INFF __builtin_huge_valf()
#define SROWS 4

// ---------------- kernel 1: zero ws + per-prototype inv-norm + class id ----
__global__ __launch_bounds__(256) void norm_init_kernel(
    const float* __restrict__ protos, const int* __restrict__ pidx,
    float* __restrict__ inv_norm, int* __restrict__ pclass,
    float* __restrict__ zero_arr, int nzero,
    double* __restrict__ contra, unsigned* __restrict__ done,
    int T, int D, int C) {
    int t = threadIdx.x;
    if (blockIdx.x == 0) {
        for (int i = t; i < nzero; i += 256) zero_arr[i] = 0.0f;
        if (t == 0) { *contra = 0.0; *done = 0u; }
    }
    int w = (blockIdx.x * 256 + t) >> 6;
    int lane = t & 63;
    if (w >= T) return;
    const float* row = protos + (size_t)w * D;
    float ss = 0.0f;
    if ((D & 3) == 0) {
        for (int k = lane * 4; k < D; k += 256) {
            float4 v = *reinterpret_cast<const float4*>(row + k);
            ss += v.x * v.x + v.y * v.y + v.z * v.z + v.w * v.w;
        }
    } else {
        for (int k = lane; k < D; k += 64) { float v = row[k]; ss += v * v; }
    }
#pragma unroll
    for (int off = 32; off > 0; off >>= 1) ss += __shfl_xor(ss, off);
    if (lane == 0) {
        inv_norm[w] = 1.0f / fmaxf(sqrtf(ss), 1e-12f);
        int lo = 0, hi = C;
        while (lo < hi) {
            int mid = (lo + hi) >> 1;
            if (pidx[2 * mid] <= w) lo = mid + 1;
            else hi = mid;
        }
        pclass[w] = lo - 1;
    }
}

// ---------------- kernel 2: per-sample min-distance, LDS-staged ------------
// Block = 256 threads stages SROWS=4 sample rows (C*P floats each) into LDS
// with coalesced float4 loads, then wave v computes row v's per-class mins.
__global__ __launch_bounds__(256) void sample_lds_kernel(
    const float* __restrict__ sims, const int* __restrict__ labels,
    const int* __restrict__ pidx,
    float* __restrict__ cls_sum, float* __restrict__ cls_n,
    float* __restrict__ sep_sum, int B, int C, int P) {
    extern __shared__ float lds[];
    int t = threadIdx.x;
    int rowlen = C * P;
    int stride = rowlen + 8;            // even pad keeps float2 alignment
    int cbase = (C + 3) & ~3;
    int* cnts = (int*)lds;
    float* rows = lds + cbase;

    for (int c = t; c < C; c += 256) cnts[c] = pidx[2 * c + 1] - pidx[2 * c];

    int b0 = blockIdx.x * SROWS;
    if ((rowlen & 3) == 0) {
        int nf4 = rowlen >> 2;
        int tot = nf4 * SROWS;
        for (int idx = t; idx < tot; idx += 256) {
            int r = (unsigned)idx / (unsigned)nf4;
            int q = idx - r * nf4;
            int b = b0 + r;
            if (b < B) {
                float4 v = reinterpret_cast<const float4*>(sims + (size_t)b * rowlen)[q];
                *reinterpret_cast<float4*>(rows + r * stride + 4 * q) = v;
            }
        }
    } else {
        int tot = rowlen * SROWS;
        for (int idx = t; idx < tot; idx += 256) {
            int r = (unsigned)idx / (unsigned)rowlen;
            int q = idx - r * rowlen;
            int b = b0 + r;
            if (b < B) rows[r * stride + q] = sims[(size_t)b * rowlen + q];
        }
    }
    __syncthreads();

    int wave = t >> 6, lane = t & 63;
    int b = b0 + wave;
    if (b >= B) return;
    int label = labels[b];
    const float* row = rows + wave * stride;
    float own = INFF, other = INFF;
    for (int cc = 0; cc < C; cc += 64) {
        int c = cc + lane;
        if (c < C) {
            int cnt = cnts[c];
            const float* cb = row + c * P;
            float m = INFF;
            if ((P & 1) == 0) {
                for (int p = 0; p < P; p += 2) {
                    float2 v = *reinterpret_cast<const float2*>(cb + p);
                    float d0 = (p < cnt) ? (1.0f - v.x) : INFF;
                    float d1 = (p + 1 < cnt) ? (1.0f - v.y) : INFF;
                    m = fminf(m, fminf(d0, d1));
                }
            } else {
                for (int p = 0; p < P; ++p) {
                    float v = cb[p];
                    m = fminf(m, (p < cnt) ? (1.0f - v) : INFF);
                }
            }
            if (c == label) own = m;
            else other = fminf(other, m);
        }
    }
#pragma unroll
    for (int off = 32; off > 0; off >>= 1) {
        own = fminf(own, __shfl_xor(own, off));
        other = fminf(other, __shfl_xor(other, off));
    }
    if (lane == 0) {
        unsafeAtomicAdd(&cls_sum[label], own);
        unsafeAtomicAdd(&cls_n[label], 1.0f);
        unsafeAtomicAdd(&sep_sum[label], fmaxf(MARGIN_C - other, 0.0f));
    }
}

// ---------------- kernel 3: pairwise cosine GEMM + fused finalize ----------
#define BLKT 64
#define KC 32
__global__ __launch_bounds__(256) void sim_kernel(
    const float* __restrict__ protos, const float* __restrict__ inv_norm,
    const int* __restrict__ pclass, const int* __restrict__ vmask,
    const int* __restrict__ pidx,
    const float* __restrict__ cls_sum, const float* __restrict__ cls_n,
    const float* __restrict__ sep_sum,
    float* __restrict__ cls_pair, double* __restrict__ contra,
    unsigned* __restrict__ done, float* __restrict__ out,
    int T, int D, int C, unsigned nblocks) {
    __shared__ float As[KC][BLKT];
    __shared__ float Bs[KC][BLKT];
    __shared__ double red[256];
    int t = threadIdx.x;
    int tx = t & 15, ty = t >> 4;
    int i0 = blockIdx.y * BLKT, j0 = blockIdx.x * BLKT;
    float acc[4][4] = {};
    for (int k0 = 0; k0 < D; k0 += KC) {
#pragma unroll
        for (int r = 0; r < (BLKT * KC) / 256; ++r) {
            int idx = t + r * 256;
            int kk = idx & (KC - 1);
            int ii = idx >> 5;  // log2(KC)
            int gk = k0 + kk;
            int gi = i0 + ii;
            As[kk][ii] = (gi < T && gk < D) ? protos[(size_t)gi * D + gk] * inv_norm[gi] : 0.0f;
            int gj = j0 + ii;
            Bs[kk][ii] = (gj < T && gk < D) ? protos[(size_t)gj * D + gk] * inv_norm[gj] : 0.0f;
        }
        __syncthreads();
#pragma unroll
        for (int kk = 0; kk < KC; ++kk) {
            float4 a = *reinterpret_cast<const float4*>(&As[kk][ty * 4]);
            float4 b = *reinterpret_cast<const float4*>(&Bs[kk][tx * 4]);
            float av[4] = {a.x, a.y, a.z, a.w};
            float bv[4] = {b.x, b.y, b.z, b.w};
#pragma unroll
            for (int e = 0; e < 4; ++e)
#pragma unroll
                for (int f = 0; f < 4; ++f) acc[e][f] += av[e] * bv[f];
        }
        __syncthreads();
    }
    // epilogue: contrastive sum (block-reduced, double atomic) + div rel sums
    float local = 0.0f;
    int iBase = i0 + ty * 4, jBase = j0 + tx * 4;
#pragma unroll
    for (int e = 0; e < 4; ++e) {
        int i = iBase + e;
        if (i >= T) continue;
        int ci = pclass[i];
        bool vi = vmask[i] != 0;
#pragma unroll
        for (int f = 0; f < 4; ++f) {
            int j = jBase + f;
            if (j >= T || j == i) continue;
            float s = acc[e][f];
            if (vi && (vmask[j] != 0)) local += s;
            if (ci >= 0 && ci == pclass[j]) {
                float rel = s - 0.5f;
                if (rel > 0.0f) unsafeAtomicAdd(&cls_pair[ci], rel);
            }
        }
    }
    red[t] = (double)local;
    __syncthreads();
#pragma unroll
    for (int s2 = 128; s2 > 0; s2 >>= 1) {
        if (t < s2) red[t] += red[t + s2];
        __syncthreads();
    }
    if (t == 0) unsafeAtomicAdd(contra, red[0]);

    // ---- fused finalize: last block to finish combines the losses ----
    __threadfence();
    __shared__ unsigned isLast;
    if (t == 0) isLast = (atomicAdd(done, 1u) == nblocks - 1) ? 1u : 0u;
    __syncthreads();
    if (!isLast || t >= 64) return;
    __threadfence();  // acquire: see other blocks' cls_pair/contra writes
    int lane = t;
    float cl = 0.0f, sp = 0.0f, dv = 0.0f;
    int nval = 0, ndv = 0, V = 0;
    for (int c = lane; c < C; c += 64) {
        float n = cls_n[c];
        if (n > 0.0f) {
            nval += 1;
            float nm = fmaxf(n, 1.0f);
            float w = 1.0f / sqrtf(n + 1e-6f);
            cl += w * (cls_sum[c] / nm);
            sp += sep_sum[c] / nm;
        }
        int cnt = pidx[2 * c + 1] - pidx[2 * c];
        if (cnt > 1) {
            ndv += 1;
            float np = (float)(cnt * (cnt - 1));
            dv += cls_pair[c] / fmaxf(np, 1.0f);
        }
    }
    for (int tt = lane; tt < T; tt += 64) V += (vmask[tt] != 0) ? 1 : 0;
#pragma unroll
    for (int off = 32; off > 0; off >>= 1) {
        cl += __shfl_xor(cl, off);
        sp += __shfl_xor(sp, off);
        dv += __shfl_xor(dv, off);
        nval += __shfl_xor(nval, off);
        ndv += __shfl_xor(ndv, off);
        V += __shfl_xor(V, off);
    }
    if (lane == 0) {
        int nv = nval > 1 ? nval : 1;
        int nd = ndv > 1 ? ndv : 1;
        float cluster = cl / (float)nv * CLST_SCALE;
        float sep = sp / (float)nv * SEP_SCALE;
        float div = dv / (float)nd * DIV_SCALE;
        long long nvp = (long long)V * (long long)V - (long long)V;
        if (nvp < 1) nvp = 1;
        float contrastive = (float)(*contra / (double)nvp) * CONTRASTIVE_SCALE;
        out[0] = cluster;
        out[1] = sep;
        out[2] = div;
        out[3] = contrastive;
        out[4] = cluster + sep + div + contrastive;
    }
}

extern "C" void kernel_launch(void* const* d_in, const int* in_sizes, int n_in,
                              void* d_out, int out_size, void* d_ws, size_t ws_size,
                              hipStream_t stream) {
    const float* sims = (const float*)d_in[0];
    const int* labels = (const int*)d_in[1];
    const float* protos = (const float*)d_in[2];
    const int* pidx = (const int*)d_in[3];
    const int* vmask = (const int*)d_in[4];
    float* out = (float*)d_out;

    int B = in_sizes[1];
    int C = in_sizes[3] / 2;
    int T = in_sizes[4];
    int D = in_sizes[2] / T;
    int P = in_sizes[0] / (B * C);

    // ws layout: [0..8) contra double; [8..12) done counter; [16..) 4 float
    // arrays of C; then inv_norm[T] f32; then pclass[T] i32. ~10 KB total.
    char* ws = (char*)d_ws;
    double* contra = (double*)ws;
    unsigned* done = (unsigned*)(ws + 8);
    float* cls_sum = (float*)(ws + 16);
    float* cls_n = cls_sum + C;
    float* sep_sum = cls_n + C;
    float* cls_pair = sep_sum + C;
    float* inv_norm = cls_pair + C;
    int* pclass = (int*)(inv_norm + T);

    // kernel 1: norm + zero-init (one wave per prototype row)
    long long nthreads = (long long)T * 64;
    int nblk1 = (int)((nthreads + 255) / 256);
    norm_init_kernel<<<dim3(nblk1), dim3(256), 0, stream>>>(
        protos, pidx, inv_norm, pclass, cls_sum, 4 * C, contra, done, T, D, C);

    // kernel 2: per-sample mins, 4 rows per block, LDS-staged
    int rowlen = C * P;
    int stride = rowlen + 8;
    int cbase = (C + 3) & ~3;
    size_t shmem = (size_t)(cbase + SROWS * stride) * sizeof(float);
    int nblk2 = (B + SROWS - 1) / SROWS;
    sample_lds_kernel<<<dim3(nblk2), dim3(256), shmem, stream>>>(
        sims, labels, pidx, cls_sum, cls_n, sep_sum, B, C, P);

    // kernel 3: cosine-sim GEMM + fused finalize
    dim3 g((T + BLKT - 1) / BLKT, (T + BLKT - 1) / BLKT);
    unsigned nblocks = g.x * g.y;
    sim_kernel<<<g, dim3(256), 0, stream>>>(
        protos, inv_norm, pclass, vmask, pidx, cls_sum, cls_n, sep_sum,
        cls_pair, contra, done, out, T, D, C, nblocks);
}

// Round 3
// 152.244 us; speedup vs baseline: 1.4431x; 1.4431x over previous
//
#include <hip/hip_runtime.h>
#include <hip/hip_bf16.h>
#include <math.h>

#define MARGIN_C 0.3f
#define CLST_SCALE 0.8f
#define SEP_SCALE 0.08f
#define DIV_SCALE 0.01f
#define CONTRASTIVE_SCALE 0.1f

#define INFF __builtin_huge_valf()
#define NVEC 16

// ---------------- K1: inv-norm per prototype row + ws zero-init ------------
__global__ __launch_bounds__(256) void norm_init_kernel(
    const float* __restrict__ protos, float* __restrict__ inv_norm,
    float* __restrict__ svec, double* __restrict__ diag,
    unsigned* __restrict__ done, int T, int D) {
    int t = threadIdx.x;
    if (blockIdx.x == 0) {
        for (int i = t; i < D; i += 256) svec[i] = 0.0f;
        if (t == 0) { *diag = 0.0; *done = 0u; }
    }
    int w = (blockIdx.x * 256 + t) >> 6;
    int lane = t & 63;
    if (w >= T) return;
    const float* row = protos + (size_t)w * D;
    float ss = 0.0f;
    if ((D & 3) == 0) {
        for (int k = lane * 4; k < D; k += 256) {
            float4 v = *reinterpret_cast<const float4*>(row + k);
            ss += v.x * v.x + v.y * v.y + v.z * v.z + v.w * v.w;
        }
    } else {
        for (int k = lane; k < D; k += 64) { float v = row[k]; ss += v * v; }
    }
#pragma unroll
    for (int off = 32; off > 0; off >>= 1) ss += __shfl_xor(ss, off);
    if (lane == 0) inv_norm[w] = 1.0f / fmaxf(sqrtf(ss), 1e-12f);
}

// ---------------- K2: per-sample min-distance, NO atomics ------------------
// One wave per sample; lane = class (chunks of 64). Tail: 2 plain stores.
__global__ __launch_bounds__(256) void sample_kernel(
    const float* __restrict__ sims, const int* __restrict__ labels,
    const int* __restrict__ pidx,
    float* __restrict__ own_arr, float* __restrict__ sep_arr,
    int B, int C, int P) {
    int gid = blockIdx.x * 256 + threadIdx.x;
    int w = gid >> 6;
    int lane = threadIdx.x & 63;
    if (w >= B) return;
    int label = labels[w];
    const float* base = sims + (size_t)w * C * P;
    float own = INFF, other = INFF;
    for (int cc = 0; cc < C; cc += 64) {
        int c = cc + lane;
        if (c < C) {
            int cnt = pidx[2 * c + 1] - pidx[2 * c];
            const float* cb = base + (size_t)c * P;
            float m = INFF;
            if ((P & 1) == 0) {
                for (int p = 0; p < P; p += 2) {
                    float2 v = *reinterpret_cast<const float2*>(cb + p);
                    float d0 = (p < cnt) ? (1.0f - v.x) : INFF;
                    float d1 = (p + 1 < cnt) ? (1.0f - v.y) : INFF;
                    m = fminf(m, fminf(d0, d1));
                }
            } else {
                for (int p = 0; p < P; ++p) {
                    float v = cb[p];
                    m = fminf(m, (p < cnt) ? (1.0f - v) : INFF);
                }
            }
            if (c == label) own = m;
            else other = fminf(other, m);
        }
    }
#pragma unroll
    for (int off = 32; off > 0; off >>= 1) {
        own = fminf(own, __shfl_xor(own, off));
        other = fminf(other, __shfl_xor(other, off));
    }
    if (lane == 0) {
        own_arr[w] = own;
        sep_arr[w] = fmaxf(MARGIN_C - other, 0.0f);
    }
}

// ---------------- K3: mega (segreduce | class-Gram | vecsum) + finalize ----
// blocks [0,C): per-class segment reduce (plain stores)
// blocks [C,2C): per-class Gram for div term
// blocks [2C,2C+NVEC): vector-sum for contrastive identity
// last block to finish: finalize
extern __shared__ float dynlds[];
__global__ __launch_bounds__(256) void mega_kernel(
    const int* __restrict__ labels, const float* __restrict__ own_arr,
    const float* __restrict__ sep_arr, const int* __restrict__ pidx,
    const int* __restrict__ vmask, const float* __restrict__ protos,
    const float* __restrict__ inv_norm,
    float* __restrict__ cls_sum, float* __restrict__ cls_n,
    float* __restrict__ sep_sum, float* __restrict__ cls_pair,
    float* __restrict__ svec, double* __restrict__ diag,
    unsigned* __restrict__ done, float* __restrict__ out,
    int B, int C, int T, int D, int P) {
    int t = threadIdx.x;
    int bid = blockIdx.x;
    int nb = 2 * C + NVEC;

    if (bid < C) {
        // ---- segment reduce for class c ----
        int c = bid;
        float o = 0.0f, sp = 0.0f, cn = 0.0f;
        for (int i = t; i < B; i += 256) {
            if (labels[i] == c) {
                o += own_arr[i];
                sp += sep_arr[i];
                cn += 1.0f;
            }
        }
#pragma unroll
        for (int off = 32; off > 0; off >>= 1) {
            o += __shfl_xor(o, off);
            sp += __shfl_xor(sp, off);
            cn += __shfl_xor(cn, off);
        }
        __shared__ float rs[3][4];
        if ((t & 63) == 0) { int wv = t >> 6; rs[0][wv] = o; rs[1][wv] = sp; rs[2][wv] = cn; }
        __syncthreads();
        if (t == 0) {
            cls_sum[c] = rs[0][0] + rs[0][1] + rs[0][2] + rs[0][3];
            sep_sum[c] = rs[1][0] + rs[1][1] + rs[1][2] + rs[1][3];
            cls_n[c] = rs[2][0] + rs[2][1] + rs[2][2] + rs[2][3];
        }
    } else if (bid < 2 * C) {
        // ---- per-class Gram (div term): rows [s0,e), n<=P ----
        int c = bid - C;
        int s0 = pidx[2 * c], e = pidx[2 * c + 1];
        int n = e - s0;
        if (n > P) n = P;
        if (n < 0) n = 0;
        int stride = D + 1;
        for (int idx = t; idx < n * D; idx += 256) {
            int i = (unsigned)idx / (unsigned)D;
            int d = idx - i * D;
            dynlds[i * stride + d] = protos[(size_t)(s0 + i) * D + d] * inv_norm[s0 + i];
        }
        __syncthreads();
        if (t < 64) {
            float tot = 0.0f;
            int npair = n * (n - 1) / 2;
            for (int l = t; l < npair; l += 64) {
                int i = 0, rem = l;
                while (rem >= n - 1 - i) { rem -= n - 1 - i; ++i; }
                int j = i + 1 + rem;
                float acc = 0.0f;
                for (int d = 0; d < D; ++d)
                    acc += dynlds[i * stride + d] * dynlds[j * stride + d];
                tot += 2.0f * fmaxf(acc - 0.5f, 0.0f);  // both (i,j) and (j,i)
            }
#pragma unroll
            for (int off = 32; off > 0; off >>= 1) tot += __shfl_xor(tot, off);
            if (t == 0) cls_pair[c] = tot;
        }
        __syncthreads();
    } else {
        // ---- vector-sum for contrastive identity ----
        int vb = bid - 2 * C;
        double ssq = 0.0;
        for (int d = t; d < D; d += 256) {
            float sv = 0.0f, sq = 0.0f;
            for (int r = vb; r < T; r += NVEC) {
                if (vmask[r] != 0) {
                    float v = protos[(size_t)r * D + d] * inv_norm[r];
                    sv += v;
                    sq += v * v;
                }
            }
            unsafeAtomicAdd(&svec[d], sv);
            ssq += (double)sq;
        }
#pragma unroll
        for (int off = 32; off > 0; off >>= 1) ssq += __shfl_xor(ssq, off);
        __shared__ double rd[4];
        if ((t & 63) == 0) rd[t >> 6] = ssq;
        __syncthreads();
        if (t == 0) unsafeAtomicAdd(diag, rd[0] + rd[1] + rd[2] + rd[3]);
    }

    // ---- fused finalize: last block combines everything ----
    __threadfence();
    __shared__ unsigned lastf;
    if (t == 0) lastf = (atomicAdd(done, 1u) == (unsigned)nb - 1u) ? 1u : 0u;
    __syncthreads();
    if (!lastf || t >= 64) return;
    __threadfence();  // acquire
    int lane = t;
    float cl = 0.0f, sp = 0.0f, dv = 0.0f;
    int nval = 0, ndv = 0, V = 0;
    for (int c = lane; c < C; c += 64) {
        float n = cls_n[c];
        if (n > 0.0f) {
            nval += 1;
            float nm = fmaxf(n, 1.0f);
            float w = 1.0f / sqrtf(n + 1e-6f);
            cl += w * (cls_sum[c] / nm);
            sp += sep_sum[c] / nm;
        }
        int cnt = pidx[2 * c + 1] - pidx[2 * c];
        if (cnt > 1) {
            ndv += 1;
            float np = (float)(cnt * (cnt - 1));
            dv += cls_pair[c] / fmaxf(np, 1.0f);
        }
    }
    for (int r = lane; r < T; r += 64) V += (vmask[r] != 0) ? 1 : 0;
    double ss2 = 0.0;
    for (int d = lane; d < D; d += 64) { double v = (double)svec[d]; ss2 += v * v; }
#pragma unroll
    for (int off = 32; off > 0; off >>= 1) {
        cl += __shfl_xor(cl, off);
        sp += __shfl_xor(sp, off);
        dv += __shfl_xor(dv, off);
        nval += __shfl_xor(nval, off);
        ndv += __shfl_xor(ndv, off);
        V += __shfl_xor(V, off);
        ss2 += __shfl_xor(ss2, off);
    }
    if (lane == 0) {
        int nv = nval > 1 ? nval : 1;
        int nd = ndv > 1 ? ndv : 1;
        float cluster = cl / (float)nv * CLST_SCALE;
        float sep = sp / (float)nv * SEP_SCALE;
        float div = dv / (float)nd * DIV_SCALE;
        double contra_sum = ss2 - *diag;  // ||sum pn||^2 - sum ||pn||^2
        long long nvp = (long long)V * (long long)V - (long long)V;
        if (nvp < 1) nvp = 1;
        float contrastive = (float)(contra_sum / (double)nvp) * CONTRASTIVE_SCALE;
        out[0] = cluster;
        out[1] = sep;
        out[2] = div;
        out[3] = contrastive;
        out[4] = cluster + sep + div + contrastive;
    }
}

extern "C" void kernel_launch(void* const* d_in, const int* in_sizes, int n_in,
                              void* d_out, int out_size, void* d_ws, size_t ws_size,
                              hipStream_t stream) {
    const float* sims = (const float*)d_in[0];
    const int* labels = (const int*)d_in[1];
    const float* protos = (const float*)d_in[2];
    const int* pidx = (const int*)d_in[3];
    const int* vmask = (const int*)d_in[4];
    float* out = (float*)d_out;

    int B = in_sizes[1];
    int C = in_sizes[3] / 2;
    int T = in_sizes[4];
    int D = in_sizes[2] / T;
    int P = in_sizes[0] / (B * C);

    // ws layout: diag double [0,8); done u32 [8,12); pad; then floats:
    // cls_sum[C], cls_n[C], sep_sum[C], cls_pair[C], svec[D], inv_norm[T],
    // own[B], sep[B].  ~140 KB total.
    char* ws = (char*)d_ws;
    double* diag = (double*)ws;
    unsigned* done = (unsigned*)(ws + 8);
    float* cls_sum = (float*)(ws + 16);
    float* cls_n = cls_sum + C;
    float* sep_sum = cls_n + C;
    float* cls_pair = sep_sum + C;
    float* svec = cls_pair + C;
    float* inv_norm = svec + D;
    float* own_arr = inv_norm + T;
    float* sep_arr = own_arr + B;

    // K1: inv-norm + zero-init
    int nblk1 = (int)(((long long)T * 64 + 255) / 256);
    norm_init_kernel<<<dim3(nblk1), dim3(256), 0, stream>>>(
        protos, inv_norm, svec, diag, done, T, D);

    // K2: per-sample mins (atomic-free)
    int nblk2 = (int)(((long long)B * 64 + 255) / 256);
    sample_kernel<<<dim3(nblk2), dim3(256), 0, stream>>>(
        sims, labels, pidx, own_arr, sep_arr, B, C, P);

    // K3: mega + fused finalize
    int nb3 = 2 * C + NVEC;
    size_t shm3 = (size_t)P * (size_t)(D + 1) * sizeof(float);
    mega_kernel<<<dim3(nb3), dim3(256), shm3, stream>>>(
        labels, own_arr, sep_arr, pidx, vmask, protos, inv_norm,
        cls_sum, cls_n, sep_sum, cls_pair, svec, diag, done, out,
        B, C, T, D, P);
}

// Round 4
// 129.544 us; speedup vs baseline: 1.6959x; 1.1752x over previous
//
#include <hip/hip_runtime.h>
#include <hip/hip_bf16.h>
#include <math.h>

#define MARGIN_C 0.3f
#define CLST_SCALE 0.8f
#define SEP_SCALE 0.08f
#define DIV_SCALE 0.01f
#define CONTRASTIVE_SCALE 0.1f

#define INFF __builtin_huge_valf()
#define NVEC 64

// ---------------- K_A: fused {ws-zero + inv-norm} | {per-sample mins} ------
// blocks [0, nb_norm): one wave per prototype row -> inv_norm
// blocks [nb_norm, ...): one wave per sample -> own/sep (plain stores)
__global__ __launch_bounds__(256) void front_kernel(
    const float* __restrict__ sims, const int* __restrict__ labels,
    const int* __restrict__ pidx, const float* __restrict__ protos,
    float* __restrict__ inv_norm, float* __restrict__ own_arr,
    float* __restrict__ sep_arr, float* __restrict__ cls3,
    float* __restrict__ svec, double* __restrict__ diag,
    unsigned* __restrict__ done, int B, int C, int T, int D, int P,
    int nb_norm) {
    int t = threadIdx.x;
    int bid = blockIdx.x;
    if (bid < nb_norm) {
        if (bid == 0) {
            for (int i = t; i < 3 * C; i += 256) cls3[i] = 0.0f;
            for (int i = t; i < D; i += 256) svec[i] = 0.0f;
            if (t == 0) { *diag = 0.0; *done = 0u; }
        }
        int w = (bid * 256 + t) >> 6;
        int lane = t & 63;
        if (w >= T) return;
        const float* row = protos + (size_t)w * D;
        float ss = 0.0f;
        if ((D & 3) == 0) {
            for (int k = lane * 4; k < D; k += 256) {
                float4 v = *reinterpret_cast<const float4*>(row + k);
                ss += v.x * v.x + v.y * v.y + v.z * v.z + v.w * v.w;
            }
        } else {
            for (int k = lane; k < D; k += 64) { float v = row[k]; ss += v * v; }
        }
#pragma unroll
        for (int off = 32; off > 0; off >>= 1) ss += __shfl_xor(ss, off);
        if (lane == 0) inv_norm[w] = 1.0f / fmaxf(sqrtf(ss), 1e-12f);
        return;
    }
    // ---- sample part ----
    int gid = (bid - nb_norm) * 256 + t;
    int w = gid >> 6;
    int lane = t & 63;
    if (w >= B) return;
    int label = labels[w];
    const float* base = sims + (size_t)w * C * P;
    float own = INFF, other = INFF;
    for (int cc = 0; cc < C; cc += 64) {
        int c = cc + lane;
        if (c < C) {
            int cnt = pidx[2 * c + 1] - pidx[2 * c];
            const float* cb = base + (size_t)c * P;
            float m = INFF;
            if ((P & 1) == 0) {
                for (int p = 0; p < P; p += 2) {
                    float2 v = *reinterpret_cast<const float2*>(cb + p);
                    float d0 = (p < cnt) ? (1.0f - v.x) : INFF;
                    float d1 = (p + 1 < cnt) ? (1.0f - v.y) : INFF;
                    m = fminf(m, fminf(d0, d1));
                }
            } else {
                for (int p = 0; p < P; ++p) {
                    float v = cb[p];
                    m = fminf(m, (p < cnt) ? (1.0f - v) : INFF);
                }
            }
            if (c == label) own = m;
            else other = fminf(other, m);
        }
    }
#pragma unroll
    for (int off = 32; off > 0; off >>= 1) {
        own = fminf(own, __shfl_xor(own, off));
        other = fminf(other, __shfl_xor(other, off));
    }
    if (lane == 0) {
        own_arr[w] = own;
        sep_arr[w] = fmaxf(MARGIN_C - other, 0.0f);
    }
}

// ---------------- K_B: {seg-histogram | class-Gram | vecsum} + finalize ----
// blocks [0,nSeg): 256 samples each, LDS float bins, spread global atomics
// blocks [nSeg,nSeg+C): per-class Gram, wave-per-pair 64-lane dots
// blocks [nSeg+C, nSeg+C+NVEC): row-range vector-sum, thread t owns dim t
__global__ __launch_bounds__(256) void reduce_kernel(
    const int* __restrict__ labels, const float* __restrict__ own_arr,
    const float* __restrict__ sep_arr, const int* __restrict__ pidx,
    const int* __restrict__ vmask, const float* __restrict__ protos,
    const float* __restrict__ inv_norm,
    float* __restrict__ cls3, float* __restrict__ cls_pair,
    float* __restrict__ svec, double* __restrict__ diag,
    unsigned* __restrict__ done, float* __restrict__ out,
    int B, int C, int T, int D, int P, int nSeg, unsigned nbTot) {
    extern __shared__ float lds[];
    __shared__ float wsum[4];
    __shared__ double rd[4];
    __shared__ unsigned lastf;
    int t = threadIdx.x;
    int bid = blockIdx.x;

    if (bid < nSeg) {
        // ---- segment histogram: 1 sample per thread ----
        for (int i = t; i < 3 * C; i += 256) lds[i] = 0.0f;
        __syncthreads();
        int i = bid * 256 + t;
        if (i < B) {
            int lb = labels[i];
            atomicAdd(&lds[lb], own_arr[i]);            // ds_add_f32
            atomicAdd(&lds[C + lb], 1.0f);
            atomicAdd(&lds[2 * C + lb], sep_arr[i]);
        }
        __syncthreads();
        for (int i2 = t; i2 < 3 * C; i2 += 256) {
            float v = lds[i2];
            if (v != 0.0f) unsafeAtomicAdd(&cls3[i2], v);
        }
    } else if (bid < nSeg + C) {
        // ---- per-class Gram (div term) ----
        int c = bid - nSeg;
        int s0 = pidx[2 * c], e = pidx[2 * c + 1];
        int n = e - s0;
        if (n > P) n = P;
        if (n < 0) n = 0;
        for (int idx = t; idx < n * D; idx += 256) {
            int i = (int)((unsigned)idx / (unsigned)D);
            lds[idx] = protos[(size_t)s0 * D + idx] * inv_norm[s0 + i];
        }
        __syncthreads();
        int wv = t >> 6, lane = t & 63;
        int npair = n * (n - 1) / 2;
        float tot = 0.0f;
        for (int l = wv; l < npair; l += 4) {
            int i = 0, rem = l;
            while (rem >= n - 1 - i) { rem -= n - 1 - i; ++i; }
            int j = i + 1 + rem;
            float acc = 0.0f;
            for (int q = lane * 4; q < D; q += 256) {
                float4 a = *reinterpret_cast<const float4*>(&lds[i * D + q]);
                float4 b = *reinterpret_cast<const float4*>(&lds[j * D + q]);
                acc += a.x * b.x + a.y * b.y + a.z * b.z + a.w * b.w;
            }
#pragma unroll
            for (int off = 32; off > 0; off >>= 1) acc += __shfl_xor(acc, off);
            tot += 2.0f * fmaxf(acc - 0.5f, 0.0f);
        }
        if (lane == 0) wsum[wv] = tot;
        __syncthreads();
        if (t == 0) cls_pair[c] = wsum[0] + wsum[1] + wsum[2] + wsum[3];
    } else {
        // ---- vector-sum for contrastive identity ----
        int vb = bid - nSeg - C;
        int rpb = (T + NVEC - 1) / NVEC;
        int r0 = vb * rpb;
        int r1 = r0 + rpb;
        if (r1 > T) r1 = T;
        double sqd = 0.0;
        for (int d = t; d < D; d += 256) {
            float sv = 0.0f, sq = 0.0f;
            for (int r = r0; r < r1; ++r) {
                if (vmask[r] != 0) {
                    float v = protos[(size_t)r * D + d] * inv_norm[r];
                    sv += v;
                    sq += v * v;
                }
            }
            if (sv != 0.0f) unsafeAtomicAdd(&svec[d], sv);
            sqd += (double)sq;
        }
#pragma unroll
        for (int off = 32; off > 0; off >>= 1) sqd += __shfl_xor(sqd, off);
        if ((t & 63) == 0) rd[t >> 6] = sqd;
        __syncthreads();
        if (t == 0) {
            double s = rd[0] + rd[1] + rd[2] + rd[3];
            if (s != 0.0) unsafeAtomicAdd(diag, s);
        }
    }

    // ---- fused finalize: last block combines everything ----
    __threadfence();
    if (t == 0) lastf = (atomicAdd(done, 1u) == nbTot - 1u) ? 1u : 0u;
    __syncthreads();
    if (!lastf || t >= 64) return;
    __threadfence();  // acquire
    int lane = t;
    float cl = 0.0f, sp = 0.0f, dv = 0.0f;
    int nval = 0, ndv = 0, V = 0;
    const float* cls_sum = cls3;
    const float* cls_n = cls3 + C;
    const float* sep_sum = cls3 + 2 * C;
    for (int c = lane; c < C; c += 64) {
        float n = cls_n[c];
        if (n > 0.0f) {
            nval += 1;
            float nm = fmaxf(n, 1.0f);
            float w = 1.0f / sqrtf(n + 1e-6f);
            cl += w * (cls_sum[c] / nm);
            sp += sep_sum[c] / nm;
        }
        int cnt = pidx[2 * c + 1] - pidx[2 * c];
        if (cnt > 1) {
            ndv += 1;
            float np = (float)(cnt * (cnt - 1));
            dv += cls_pair[c] / fmaxf(np, 1.0f);
        }
    }
    for (int r = lane; r < T; r += 64) V += (vmask[r] != 0) ? 1 : 0;
    double ss2 = 0.0;
    for (int d = lane; d < D; d += 64) { double v = (double)svec[d]; ss2 += v * v; }
#pragma unroll
    for (int off = 32; off > 0; off >>= 1) {
        cl += __shfl_xor(cl, off);
        sp += __shfl_xor(sp, off);
        dv += __shfl_xor(dv, off);
        nval += __shfl_xor(nval, off);
        ndv += __shfl_xor(ndv, off);
        V += __shfl_xor(V, off);
        ss2 += __shfl_xor(ss2, off);
    }
    if (lane == 0) {
        int nv = nval > 1 ? nval : 1;
        int nd = ndv > 1 ? ndv : 1;
        float cluster = cl / (float)nv * CLST_SCALE;
        float sep = sp / (float)nv * SEP_SCALE;
        float div = dv / (float)nd * DIV_SCALE;
        double contra_sum = ss2 - *diag;  // ||sum pn||^2 - sum ||pn||^2
        long long nvp = (long long)V * (long long)V - (long long)V;
        if (nvp < 1) nvp = 1;
        float contrastive = (float)(contra_sum / (double)nvp) * CONTRASTIVE_SCALE;
        out[0] = cluster;
        out[1] = sep;
        out[2] = div;
        out[3] = contrastive;
        out[4] = cluster + sep + div + contrastive;
    }
}

extern "C" void kernel_launch(void* const* d_in, const int* in_sizes, int n_in,
                              void* d_out, int out_size, void* d_ws, size_t ws_size,
                              hipStream_t stream) {
    const float* sims = (const float*)d_in[0];
    const int* labels = (const int*)d_in[1];
    const float* protos = (const float*)d_in[2];
    const int* pidx = (const int*)d_in[3];
    const int* vmask = (const int*)d_in[4];
    float* out = (float*)d_out;

    int B = in_sizes[1];
    int C = in_sizes[3] / 2;
    int T = in_sizes[4];
    int D = in_sizes[2] / T;
    int P = in_sizes[0] / (B * C);

    // ws: diag f64 [0,8); done u32 [8,12); pad; floats: cls3[3C], cls_pair[C],
    // svec[D], inv_norm[T], own[B], sep[B].
    char* ws = (char*)d_ws;
    double* diag = (double*)ws;
    unsigned* done = (unsigned*)(ws + 8);
    float* cls3 = (float*)(ws + 16);
    float* cls_pair = cls3 + 3 * C;
    float* svec = cls_pair + C;
    float* inv_norm = svec + D;
    float* own_arr = inv_norm + T;
    float* sep_arr = own_arr + B;

    // K_A: fused norm-init + sample
    int nb_norm = (int)(((long long)T * 64 + 255) / 256);
    int nb_samp = (int)(((long long)B * 64 + 255) / 256);
    front_kernel<<<dim3(nb_norm + nb_samp), dim3(256), 0, stream>>>(
        sims, labels, pidx, protos, inv_norm, own_arr, sep_arr,
        cls3, svec, diag, done, B, C, T, D, P, nb_norm);

    // K_B: reduce + finalize
    int nSeg = (B + 255) / 256;
    unsigned nbTot = (unsigned)(nSeg + C + NVEC);
    int ldsf = 3 * C;
    if (P * D > ldsf) ldsf = P * D;
    size_t shm = (size_t)ldsf * sizeof(float);
    reduce_kernel<<<dim3(nbTot), dim3(256), shm, stream>>>(
        labels, own_arr, sep_arr, pidx, vmask, protos, inv_norm,
        cls3, cls_pair, svec, diag, done, out, B, C, T, D, P, nSeg, nbTot);
}

// Round 6
// 128.925 us; speedup vs baseline: 1.7041x; 1.0048x over previous
//
#include <hip/hip_runtime.h>
#include <hip/hip_bf16.h>
#include <math.h>

#define MARGIN_C 0.3f
#define CLST_SCALE 0.8f
#define SEP_SCALE 0.08f
#define DIV_SCALE 0.01f
#define CONTRASTIVE_SCALE 0.1f

#define INFF __builtin_huge_valf()
#define NVEC 64
#define SROWS 4

// ---------------- K_A: fused {ws-zero + inv-norm} | {per-sample mins} ------
// blocks [0, nb_norm): one wave per prototype row -> inv_norm
// blocks [nb_norm, ...): SROWS samples per block, LDS-staged coalesced float4
extern __shared__ float fk_lds[];
__global__ __launch_bounds__(256) void front_kernel(
    const float* __restrict__ sims, const int* __restrict__ labels,
    const int* __restrict__ pidx, const float* __restrict__ protos,
    float* __restrict__ inv_norm, float* __restrict__ own_arr,
    float* __restrict__ sep_arr, float* __restrict__ cls3,
    float* __restrict__ svec, double* __restrict__ diag,
    unsigned* __restrict__ done, int B, int C, int T, int D, int P,
    int nb_norm) {
    int t = threadIdx.x;
    int bid = blockIdx.x;
    if (bid < nb_norm) {
        if (bid == 0) {
            for (int i = t; i < 3 * C; i += 256) cls3[i] = 0.0f;
            for (int i = t; i < D; i += 256) svec[i] = 0.0f;
            if (t == 0) { *diag = 0.0; *done = 0u; }
        }
        int w = (bid * 256 + t) >> 6;
        int lane = t & 63;
        if (w >= T) return;
        const float* row = protos + (size_t)w * D;
        float ss = 0.0f;
        if ((D & 3) == 0) {
            for (int k = lane * 4; k < D; k += 256) {
                float4 v = *reinterpret_cast<const float4*>(row + k);
                ss += v.x * v.x + v.y * v.y + v.z * v.z + v.w * v.w;
            }
        } else {
            for (int k = lane; k < D; k += 64) { float v = row[k]; ss += v * v; }
        }
#pragma unroll
        for (int off = 32; off > 0; off >>= 1) ss += __shfl_xor(ss, off);
        if (lane == 0) inv_norm[w] = 1.0f / fmaxf(sqrtf(ss), 1e-12f);
        return;
    }
    // ---- sample part: stage SROWS rows into LDS with coalesced float4 ----
    int rowlen = C * P;
    int stride = ((rowlen + 3) & ~3) + 8;  // float4-aligned + pad
    int cbase = (C + 3) & ~3;
    int* cnts = (int*)fk_lds;
    float* rows = fk_lds + cbase;

    for (int c = t; c < C; c += 256) cnts[c] = pidx[2 * c + 1] - pidx[2 * c];

    int b0 = (bid - nb_norm) * SROWS;
    if ((rowlen & 3) == 0) {
        int nf4 = rowlen >> 2;
#pragma unroll
        for (int r = 0; r < SROWS; ++r) {
            int b = b0 + r;
            if (b >= B) break;
            const float4* src = reinterpret_cast<const float4*>(sims + (size_t)b * rowlen);
            float* dst = rows + r * stride;
            for (int q = t; q < nf4; q += 256)
                *reinterpret_cast<float4*>(dst + 4 * q) = src[q];
        }
    } else {
#pragma unroll
        for (int r = 0; r < SROWS; ++r) {
            int b = b0 + r;
            if (b >= B) break;
            const float* src = sims + (size_t)b * rowlen;
            float* dst = rows + r * stride;
            for (int q = t; q < rowlen; q += 256) dst[q] = src[q];
        }
    }
    __syncthreads();

    int wave = t >> 6, lane = t & 63;
    int b = b0 + wave;
    if (b >= B) return;
    int label = labels[b];
    const float* row = rows + wave * stride;
    float own = INFF, other = INFF;
    for (int cc = 0; cc < C; cc += 64) {
        int c = cc + lane;
        if (c < C) {
            int cnt = cnts[c];
            const float* cb = row + c * P;
            float m = INFF;
            if ((P & 1) == 0) {
                for (int p = 0; p < P; p += 2) {
                    float2 v = *reinterpret_cast<const float2*>(cb + p);
                    float d0 = (p < cnt) ? (1.0f - v.x) : INFF;
                    float d1 = (p + 1 < cnt) ? (1.0f - v.y) : INFF;
                    m = fminf(m, fminf(d0, d1));
                }
            } else {
                for (int p = 0; p < P; ++p) {
                    float v = cb[p];
                    m = fminf(m, (p < cnt) ? (1.0f - v) : INFF);
                }
            }
            if (c == label) own = m;
            else other = fminf(other, m);
        }
    }
#pragma unroll
    for (int off = 32; off > 0; off >>= 1) {
        own = fminf(own, __shfl_xor(own, off));
        other = fminf(other, __shfl_xor(other, off));
    }
    if (lane == 0) {
        own_arr[b] = own;
        sep_arr[b] = fmaxf(MARGIN_C - other, 0.0f);
    }
}

// ---------------- K_B: {seg-histogram | class-Gram | vecsum} + finalize ----
extern __shared__ float rk_lds[];
__global__ __launch_bounds__(256) void reduce_kernel(
    const int* __restrict__ labels, const float* __restrict__ own_arr,
    const float* __restrict__ sep_arr, const int* __restrict__ pidx,
    const int* __restrict__ vmask, const float* __restrict__ protos,
    const float* __restrict__ inv_norm,
    float* __restrict__ cls3, float* __restrict__ cls_pair,
    float* __restrict__ svec, double* __restrict__ diag,
    unsigned* __restrict__ done, float* __restrict__ out,
    int B, int C, int T, int D, int P, int nSeg, unsigned nbTot) {
    __shared__ float wsum[4];
    __shared__ double rd[4];
    __shared__ unsigned lastf;
    int t = threadIdx.x;
    int bid = blockIdx.x;

    if (bid < nSeg) {
        // ---- segment histogram: 1 sample per thread, LDS bins ----
        for (int i = t; i < 3 * C; i += 256) rk_lds[i] = 0.0f;
        __syncthreads();
        int i = bid * 256 + t;
        if (i < B) {
            int lb = labels[i];
            atomicAdd(&rk_lds[lb], own_arr[i]);
            atomicAdd(&rk_lds[C + lb], 1.0f);
            atomicAdd(&rk_lds[2 * C + lb], sep_arr[i]);
        }
        __syncthreads();
        for (int i2 = t; i2 < 3 * C; i2 += 256) {
            float v = rk_lds[i2];
            if (v != 0.0f) unsafeAtomicAdd(&cls3[i2], v);
        }
    } else if (bid < nSeg + C) {
        // ---- per-class Gram (div term) ----
        int c = bid - nSeg;
        int s0 = pidx[2 * c], e = pidx[2 * c + 1];
        int n = e - s0;
        if (n > P) n = P;
        if (n < 0) n = 0;
        for (int idx = t; idx < n * D; idx += 256) {
            int i = (int)((unsigned)idx / (unsigned)D);
            rk_lds[idx] = protos[(size_t)s0 * D + idx] * inv_norm[s0 + i];
        }
        __syncthreads();
        int wv = t >> 6, lane = t & 63;
        int npair = n * (n - 1) / 2;
        float tot = 0.0f;
        for (int l = wv; l < npair; l += 4) {
            int i = 0, rem = l;
            while (rem >= n - 1 - i) { rem -= n - 1 - i; ++i; }
            int j = i + 1 + rem;
            float acc = 0.0f;
            for (int q = lane * 4; q < D; q += 256) {
                float4 a = *reinterpret_cast<const float4*>(&rk_lds[i * D + q]);
                float4 b = *reinterpret_cast<const float4*>(&rk_lds[j * D + q]);
                acc += a.x * b.x + a.y * b.y + a.z * b.z + a.w * b.w;
            }
#pragma unroll
            for (int off = 32; off > 0; off >>= 1) acc += __shfl_xor(acc, off);
            tot += 2.0f * fmaxf(acc - 0.5f, 0.0f);
        }
        if (lane == 0) wsum[wv] = tot;
        __syncthreads();
        if (t == 0) cls_pair[c] = wsum[0] + wsum[1] + wsum[2] + wsum[3];
    } else {
        // ---- vector-sum for contrastive identity ----
        int vb = bid - nSeg - C;
        int rpb = (T + NVEC - 1) / NVEC;
        int r0 = vb * rpb;
        int r1 = r0 + rpb;
        if (r1 > T) r1 = T;
        double sqd = 0.0;
        for (int d = t; d < D; d += 256) {
            float sv = 0.0f, sq = 0.0f;
            for (int r = r0; r < r1; ++r) {
                if (vmask[r] != 0) {
                    float v = protos[(size_t)r * D + d] * inv_norm[r];
                    sv += v;
                    sq += v * v;
                }
            }
            if (sv != 0.0f) unsafeAtomicAdd(&svec[d], sv);
            sqd += (double)sq;
        }
#pragma unroll
        for (int off = 32; off > 0; off >>= 1) sqd += __shfl_xor(sqd, off);
        if ((t & 63) == 0) rd[t >> 6] = sqd;
        __syncthreads();
        if (t == 0) {
            double s = rd[0] + rd[1] + rd[2] + rd[3];
            if (s != 0.0) unsafeAtomicAdd(diag, s);
        }
    }

    // ---- fused finalize: last block combines everything ----
    __threadfence();
    if (t == 0) lastf = (atomicAdd(done, 1u) == nbTot - 1u) ? 1u : 0u;
    __syncthreads();
    if (!lastf || t >= 64) return;
    __threadfence();  // acquire
    int lane = t;
    float cl = 0.0f, sp = 0.0f, dv = 0.0f;
    int nval = 0, ndv = 0, V = 0;
    const float* cls_sum = cls3;
    const float* cls_n = cls3 + C;
    const float* sep_sum = cls3 + 2 * C;
    for (int c = lane; c < C; c += 64) {
        float n = cls_n[c];
        if (n > 0.0f) {
            nval += 1;
            float nm = fmaxf(n, 1.0f);
            float w = 1.0f / sqrtf(n + 1e-6f);
            cl += w * (cls_sum[c] / nm);
            sp += sep_sum[c] / nm;
        }
        int cnt = pidx[2 * c + 1] - pidx[2 * c];
        if (cnt > 1) {
            ndv += 1;
            float np = (float)(cnt * (cnt - 1));
            dv += cls_pair[c] / fmaxf(np, 1.0f);
        }
    }
    for (int r = lane; r < T; r += 64) V += (vmask[r] != 0) ? 1 : 0;
    double ss2 = 0.0;
    for (int d = lane; d < D; d += 64) { double v = (double)svec[d]; ss2 += v * v; }
#pragma unroll
    for (int off = 32; off > 0; off >>= 1) {
        cl += __shfl_xor(cl, off);
        sp += __shfl_xor(sp, off);
        dv += __shfl_xor(dv, off);
        nval += __shfl_xor(nval, off);
        ndv += __shfl_xor(ndv, off);
        V += __shfl_xor(V, off);
        ss2 += __shfl_xor(ss2, off);
    }
    if (lane == 0) {
        int nv = nval > 1 ? nval : 1;
        int nd = ndv > 1 ? ndv : 1;
        float cluster = cl / (float)nv * CLST_SCALE;
        float sep = sp / (float)nv * SEP_SCALE;
        float div = dv / (float)nd * DIV_SCALE;
        double contra_sum = ss2 - *diag;  // ||sum pn||^2 - sum ||pn||^2
        long long nvp = (long long)V * (long long)V - (long long)V;
        if (nvp < 1) nvp = 1;
        float contrastive = (float)(contra_sum / (double)nvp) * CONTRASTIVE_SCALE;
        out[0] = cluster;
        out[1] = sep;
        out[2] = div;
        out[3] = contrastive;
        out[4] = cluster + sep + div + contrastive;
    }
}

extern "C" void kernel_launch(void* const* d_in, const int* in_sizes, int n_in,
                              void* d_out, int out_size, void* d_ws, size_t ws_size,
                              hipStream_t stream) {
    const float* sims = (const float*)d_in[0];
    const int* labels = (const int*)d_in[1];
    const float* protos = (const float*)d_in[2];
    const int* pidx = (const int*)d_in[3];
    const int* vmask = (const int*)d_in[4];
    float* out = (float*)d_out;

    int B = in_sizes[1];
    int C = in_sizes[3] / 2;
    int T = in_sizes[4];
    int D = in_sizes[2] / T;
    int P = in_sizes[0] / (B * C);

    // ws: diag f64 [0,8); done u32 [8,12); pad; floats: cls3[3C], cls_pair[C],
    // svec[D], inv_norm[T], own[B], sep[B].
    char* ws = (char*)d_ws;
    double* diag = (double*)ws;
    unsigned* done = (unsigned*)(ws + 8);
    float* cls3 = (float*)(ws + 16);
    float* cls_pair = cls3 + 3 * C;
    float* svec = cls_pair + C;
    float* inv_norm = svec + D;
    float* own_arr = inv_norm + T;
    float* sep_arr = own_arr + B;

    // K_A: fused norm-init + LDS-staged sample
    int nb_norm = (int)(((long long)T * 64 + 255) / 256);
    int nb_samp = (B + SROWS - 1) / SROWS;
    int rowlen = C * P;
    int stride = ((rowlen + 3) & ~3) + 8;
    int cbase = (C + 3) & ~3;
    size_t shmA = (size_t)(cbase + SROWS * stride) * sizeof(float);
    front_kernel<<<dim3(nb_norm + nb_samp), dim3(256), shmA, stream>>>(
        sims, labels, pidx, protos, inv_norm, own_arr, sep_arr,
        cls3, svec, diag, done, B, C, T, D, P, nb_norm);

    // K_B: reduce + finalize
    int nSeg = (B + 255) / 256;
    unsigned nbTot = (unsigned)(nSeg + C + NVEC);
    int ldsf = 3 * C;
    if (P * D > ldsf) ldsf = P * D;
    size_t shmB = (size_t)ldsf * sizeof(float);
    reduce_kernel<<<dim3(nbTot), dim3(256), shmB, stream>>>(
        labels, own_arr, sep_arr, pidx, vmask, protos, inv_norm,
        cls3, cls_pair, svec, diag, done, out, B, C, T, D, P, nSeg, nbTot);
}

// Round 7
// 128.550 us; speedup vs baseline: 1.7091x; 1.0029x over previous
//
#include <hip/hip_runtime.h>
#include <hip/hip_bf16.h>
#include <math.h>

#define MARGIN_C 0.3f
#define CLST_SCALE 0.8f
#define SEP_SCALE 0.08f
#define DIV_SCALE 0.01f
#define CONTRASTIVE_SCALE 0.1f

#define INFF __builtin_huge_valf()
#define NVEC 64

// ---------------- K_A: per-sample min-distance, wave-per-sample ------------
// 16 waves/block; wave w stages ONLY its own sims row into its own LDS slab
// (coalesced float4, 64 lanes x 16B), then computes per-class mins from LDS.
// Tail: 2 plain stores. Block 0 additionally zero-inits the ws accumulators.
extern __shared__ float fk_lds[];
__global__ __launch_bounds__(1024) void front_kernel(
    const float* __restrict__ sims, const int* __restrict__ labels,
    const int* __restrict__ pidx,
    float* __restrict__ own_arr, float* __restrict__ sep_arr,
    float* __restrict__ cls3, float* __restrict__ svec,
    double* __restrict__ diag, unsigned* __restrict__ done,
    int B, int C, int D, int P, int strideF) {
    int t = threadIdx.x;
    int nthr = blockDim.x;
    int wave = t >> 6, lane = t & 63;
    int bid = blockIdx.x;
    if (bid == 0) {
        for (int i = t; i < 3 * C; i += nthr) cls3[i] = 0.0f;
        for (int i = t; i < D; i += nthr) svec[i] = 0.0f;
        if (t == 0) { *diag = 0.0; *done = 0u; }
    }
    int rowlen = C * P;
    int rows = nthr >> 6;
    int b = bid * rows + wave;
    float* row = fk_lds + wave * strideF;
    if (b < B) {
        const float* src = sims + (size_t)b * rowlen;
        if ((rowlen & 3) == 0) {
            int nf4 = rowlen >> 2;
            const float4* s4 = reinterpret_cast<const float4*>(src);
            for (int q = lane; q < nf4; q += 64)
                *reinterpret_cast<float4*>(row + 4 * q) = s4[q];
        } else {
            for (int q = lane; q < rowlen; q += 64) row[q] = src[q];
        }
    }
    __syncthreads();
    if (b >= B) return;
    int label = labels[b];
    float own = INFF, other = INFF;
    for (int cc = 0; cc < C; cc += 64) {
        int c = cc + lane;
        if (c < C) {
            int cnt = pidx[2 * c + 1] - pidx[2 * c];
            const float* cb = row + c * P;
            float m = INFF;
            if ((P & 1) == 0) {
                for (int p = 0; p < P; p += 2) {
                    float2 v = *reinterpret_cast<const float2*>(cb + p);
                    float d0 = (p < cnt) ? (1.0f - v.x) : INFF;
                    float d1 = (p + 1 < cnt) ? (1.0f - v.y) : INFF;
                    m = fminf(m, fminf(d0, d1));
                }
            } else {
                for (int p = 0; p < P; ++p) {
                    float v = cb[p];
                    m = fminf(m, (p < cnt) ? (1.0f - v) : INFF);
                }
            }
            if (c == label) own = m;
            else other = fminf(other, m);
        }
    }
#pragma unroll
    for (int off = 32; off > 0; off >>= 1) {
        own = fminf(own, __shfl_xor(own, off));
        other = fminf(other, __shfl_xor(other, off));
    }
    if (lane == 0) {
        own_arr[b] = own;
        sep_arr[b] = fmaxf(MARGIN_C - other, 0.0f);
    }
}

// ---------------- K_B: {seg-histogram | class-Gram | vecsum} + finalize ----
// Gram/vecsum blocks compute the norms of rows they stage themselves
// (normalization factors out of the dot products) -> no norm pre-pass.
extern __shared__ float rk_lds[];
__global__ __launch_bounds__(256) void reduce_kernel(
    const int* __restrict__ labels, const float* __restrict__ own_arr,
    const float* __restrict__ sep_arr, const int* __restrict__ pidx,
    const int* __restrict__ vmask, const float* __restrict__ protos,
    float* __restrict__ cls3, float* __restrict__ cls_pair,
    float* __restrict__ svec, double* __restrict__ diag,
    unsigned* __restrict__ done, float* __restrict__ out,
    int B, int C, int T, int D, int P, int nSeg, int rpb, int chunk,
    unsigned nbTot) {
    __shared__ float wsum[4];
    __shared__ double rd[4];
    __shared__ float invn[128];
    __shared__ int vmf[128];
    __shared__ unsigned lastf;
    int t = threadIdx.x, bid = blockIdx.x;
    int wv = t >> 6, lane = t & 63;

    if (bid < nSeg) {
        // ---- segment histogram: 1 sample per thread, LDS bins ----
        for (int i = t; i < 3 * C; i += 256) rk_lds[i] = 0.0f;
        __syncthreads();
        int i = bid * 256 + t;
        if (i < B) {
            int lb = labels[i];
            atomicAdd(&rk_lds[lb], own_arr[i]);
            atomicAdd(&rk_lds[C + lb], 1.0f);
            atomicAdd(&rk_lds[2 * C + lb], sep_arr[i]);
        }
        __syncthreads();
        for (int i2 = t; i2 < 3 * C; i2 += 256) {
            float v = rk_lds[i2];
            if (v != 0.0f) unsafeAtomicAdd(&cls3[i2], v);
        }
    } else if (bid < nSeg + C) {
        // ---- per-class Gram (div term), self-normalized ----
        int c = bid - nSeg;
        int s0 = pidx[2 * c], e = pidx[2 * c + 1];
        int n = e - s0;
        if (n > P) n = P;
        if (n > 128) n = 128;
        if (n < 0) n = 0;
        for (int idx = t; idx < n * D; idx += 256)
            rk_lds[idx] = protos[(size_t)s0 * D + idx];
        __syncthreads();
        for (int i = wv; i < n; i += 4) {
            float ss = 0.0f;
            for (int q = lane; q < D; q += 64) { float v = rk_lds[i * D + q]; ss += v * v; }
#pragma unroll
            for (int off = 32; off > 0; off >>= 1) ss += __shfl_xor(ss, off);
            if (lane == 0) invn[i] = 1.0f / fmaxf(sqrtf(ss), 1e-12f);
        }
        __syncthreads();
        int npair = n * (n - 1) / 2;
        float tot = 0.0f;
        for (int l = wv; l < npair; l += 4) {
            int i = 0, rem = l;
            while (rem >= n - 1 - i) { rem -= n - 1 - i; ++i; }
            int j = i + 1 + rem;
            float acc = 0.0f;
            if ((D & 3) == 0) {
                for (int q = lane * 4; q < D; q += 256) {
                    float4 a = *reinterpret_cast<const float4*>(&rk_lds[i * D + q]);
                    float4 b = *reinterpret_cast<const float4*>(&rk_lds[j * D + q]);
                    acc += a.x * b.x + a.y * b.y + a.z * b.z + a.w * b.w;
                }
            } else {
                for (int q = lane; q < D; q += 64) acc += rk_lds[i * D + q] * rk_lds[j * D + q];
            }
#pragma unroll
            for (int off = 32; off > 0; off >>= 1) acc += __shfl_xor(acc, off);
            tot += 2.0f * fmaxf(acc * invn[i] * invn[j] - 0.5f, 0.0f);
        }
        if (lane == 0) wsum[wv] = tot;
        __syncthreads();
        if (t == 0) cls_pair[c] = wsum[0] + wsum[1] + wsum[2] + wsum[3];
    } else {
        // ---- vector-sum for contrastive identity, self-normalized ----
        int vb = bid - nSeg - C;
        int r0 = vb * rpb, r1 = r0 + rpb;
        if (r1 > T) r1 = T;
        double sqd = 0.0;
        for (int base = r0; base < r1; base += chunk) {
            int nr = r1 - base;
            if (nr > chunk) nr = chunk;
            for (int idx = t; idx < nr * D; idx += 256)
                rk_lds[idx] = protos[(size_t)base * D + idx];
            __syncthreads();
            for (int r = wv; r < nr; r += 4) {
                float ss = 0.0f;
                for (int q = lane; q < D; q += 64) { float v = rk_lds[r * D + q]; ss += v * v; }
#pragma unroll
                for (int off = 32; off > 0; off >>= 1) ss += __shfl_xor(ss, off);
                if (lane == 0) {
                    invn[r] = 1.0f / fmaxf(sqrtf(ss), 1e-12f);
                    vmf[r] = vmask[base + r];
                }
            }
            __syncthreads();
            for (int d = t; d < D; d += 256) {
                float sv = 0.0f, sq = 0.0f;
                for (int r = 0; r < nr; ++r) {
                    if (vmf[r] != 0) {
                        float v = rk_lds[r * D + d] * invn[r];
                        sv += v;
                        sq += v * v;
                    }
                }
                if (sv != 0.0f) unsafeAtomicAdd(&svec[d], sv);
                sqd += (double)sq;
            }
            __syncthreads();  // protect LDS before next chunk overwrite
        }
#pragma unroll
        for (int off = 32; off > 0; off >>= 1) sqd += __shfl_xor(sqd, off);
        if ((t & 63) == 0) rd[t >> 6] = sqd;
        __syncthreads();
        if (t == 0) {
            double s = rd[0] + rd[1] + rd[2] + rd[3];
            if (s != 0.0) unsafeAtomicAdd(diag, s);
        }
    }

    // ---- fused finalize: last block combines everything ----
    __threadfence();
    if (t == 0) lastf = (atomicAdd(done, 1u) == nbTot - 1u) ? 1u : 0u;
    __syncthreads();
    if (!lastf || t >= 64) return;
    __threadfence();  // acquire: see other blocks' accumulator writes
    int lane2 = t;
    float cl = 0.0f, sp = 0.0f, dv = 0.0f;
    int nval = 0, ndv = 0, V = 0;
    const float* cls_sum = cls3;
    const float* cls_n = cls3 + C;
    const float* sep_sum = cls3 + 2 * C;
    for (int c = lane2; c < C; c += 64) {
        float n = cls_n[c];
        if (n > 0.0f) {
            nval += 1;
            float nm = fmaxf(n, 1.0f);
            float w = 1.0f / sqrtf(n + 1e-6f);
            cl += w * (cls_sum[c] / nm);
            sp += sep_sum[c] / nm;
        }
        int cnt = pidx[2 * c + 1] - pidx[2 * c];
        if (cnt > 1) {
            ndv += 1;
            float np = (float)(cnt * (cnt - 1));
            dv += cls_pair[c] / fmaxf(np, 1.0f);
        }
    }
    for (int r = lane2; r < T; r += 64) V += (vmask[r] != 0) ? 1 : 0;
    double ss2 = 0.0;
    for (int d = lane2; d < D; d += 64) { double v = (double)svec[d]; ss2 += v * v; }
#pragma unroll
    for (int off = 32; off > 0; off >>= 1) {
        cl += __shfl_xor(cl, off);
        sp += __shfl_xor(sp, off);
        dv += __shfl_xor(dv, off);
        nval += __shfl_xor(nval, off);
        ndv += __shfl_xor(ndv, off);
        V += __shfl_xor(V, off);
        ss2 += __shfl_xor(ss2, off);
    }
    if (lane2 == 0) {
        int nv = nval > 1 ? nval : 1;
        int nd = ndv > 1 ? ndv : 1;
        float cluster = cl / (float)nv * CLST_SCALE;
        float sep = sp / (float)nv * SEP_SCALE;
        float div = dv / (float)nd * DIV_SCALE;
        double contra_sum = ss2 - *diag;  // ||sum pn||^2 - sum ||pn||^2
        long long nvp = (long long)V * (long long)V - (long long)V;
        if (nvp < 1) nvp = 1;
        float contrastive = (float)(contra_sum / (double)nvp) * CONTRASTIVE_SCALE;
        out[0] = cluster;
        out[1] = sep;
        out[2] = div;
        out[3] = contrastive;
        out[4] = cluster + sep + div + contrastive;
    }
}

extern "C" void kernel_launch(void* const* d_in, const int* in_sizes, int n_in,
                              void* d_out, int out_size, void* d_ws, size_t ws_size,
                              hipStream_t stream) {
    const float* sims = (const float*)d_in[0];
    const int* labels = (const int*)d_in[1];
    const float* protos = (const float*)d_in[2];
    const int* pidx = (const int*)d_in[3];
    const int* vmask = (const int*)d_in[4];
    float* out = (float*)d_out;

    int B = in_sizes[1];
    int C = in_sizes[3] / 2;
    int T = in_sizes[4];
    int D = in_sizes[2] / T;
    int P = in_sizes[0] / (B * C);

    // ws: diag f64 [0,8); done u32 [8,12); pad; floats: cls3[3C], cls_pair[C],
    // svec[D], own[B], sep[B].
    char* ws = (char*)d_ws;
    double* diag = (double*)ws;
    unsigned* done = (unsigned*)(ws + 8);
    float* cls3 = (float*)(ws + 16);
    float* cls_pair = cls3 + 3 * C;
    float* svec = cls_pair + C;
    float* own_arr = svec + D;
    float* sep_arr = own_arr + B;

    // K_A: wave-per-sample front. 16 waves/block (1024 thr) if LDS permits.
    int rowlen = C * P;
    int strideF = ((rowlen + 3) & ~3) + 8;
    int rowsPB = 65536 / (strideF * 4);
    if (rowsPB > 16) rowsPB = 16;
    if (rowsPB < 1) rowsPB = 1;
    int blkA = rowsPB * 64;
    int nbA = (B + rowsPB - 1) / rowsPB;
    size_t shmA = (size_t)rowsPB * strideF * sizeof(float);
    front_kernel<<<dim3(nbA), dim3(blkA), shmA, stream>>>(
        sims, labels, pidx, own_arr, sep_arr, cls3, svec, diag, done,
        B, C, D, P, strideF);

    // K_B: reduce + finalize (self-normalizing gram/vecsum)
    int nSeg = (B + 255) / 256;
    int rpb = (T + NVEC - 1) / NVEC;
    int chunk = 57344 / (D * 4);
    if (chunk < 1) chunk = 1;
    if (chunk > rpb) chunk = rpb;
    if (chunk > 128) chunk = 128;
    int gramRows = (P < 128) ? P : 128;
    int ldsF = 3 * C;
    if (gramRows * D > ldsF) ldsF = gramRows * D;
    if (chunk * D > ldsF) ldsF = chunk * D;
    size_t shmB = (size_t)ldsF * sizeof(float);
    unsigned nbTot = (unsigned)(nSeg + C + NVEC);
    reduce_kernel<<<dim3(nbTot), dim3(256), shmB, stream>>>(
        labels, own_arr, sep_arr, pidx, vmask, protos,
        cls3, cls_pair, svec, diag, done, out,
        B, C, T, D, P, nSeg, rpb, chunk, nbTot);
}